// Round 7
// baseline (1168.410 us; speedup 1.0000x reference)
//
#include <hip/hip_runtime.h>
#include <cstdint>
#include <cstddef>

// ---------------------------------------------------------------------------
// GCN forward. CSR built on-device (rows padded %4, packed (col,val) pairs).
// SpMM gathers per-row int16-quantized rows, accumulates f32, writes
// interleaved bf16 hi/lo planes (Zhl) = next GEMM's A operand.
// GEMM: 3-term split-MFMA (Ahi*Bhi + Ahi*Blo + Alo*Bhi), A & B interleaved
// hi8|lo8 bf16 in LDS with XOR-8 slot swizzle (linear LDS dest +
// pre-swizzled global source). ROUND 7: 2-phase double-buffered K-loop —
// stage(t+1) issued BEFORE compute(t), single barrier per step, so the
// vmcnt drain at the barrier lands after ~400cyc of MFMA instead of before.
// Fused per-row int16 quantization epilogue.
// ---------------------------------------------------------------------------

#define SCAN_B 1024

typedef __attribute__((ext_vector_type(8))) short short8_t;
typedef __attribute__((ext_vector_type(4))) short short4_t;
typedef __attribute__((ext_vector_type(4))) float f32x4;

__device__ __forceinline__ short bf16_hi(float x) {
    union { float f; unsigned u; } c; c.f = x;
    return (short)(c.u >> 16);
}
__device__ __forceinline__ float bf16_f32(short h) {
    union { float f; unsigned u; } c; c.u = ((unsigned)(unsigned short)h) << 16;
    return c.f;
}

__device__ __forceinline__ void gload_lds16(const void* g, void* l) {
    __builtin_amdgcn_global_load_lds(
        (const __attribute__((address_space(1))) void*)g,
        (__attribute__((address_space(3))) void*)l, 16, 0, 0);
}

// ---------------- CSR construction (rows padded to %4) ----------------

__global__ void count_rows_k(const int* __restrict__ row, int* __restrict__ deg, int E) {
    int e = blockIdx.x * blockDim.x + threadIdx.x;
    if (e < E) atomicAdd(&deg[row[e]], 1);
}

__global__ __launch_bounds__(SCAN_B) void scan1_k(const int* __restrict__ deg,
                                                  int* __restrict__ part,
                                                  int* __restrict__ bsum, int n) {
    __shared__ int buf[SCAN_B];
    int tid = threadIdx.x;
    int i = blockIdx.x * SCAN_B + tid;
    int v = (i < n) ? ((deg[i] + 3) & ~3) : 0;     // padded degree
    buf[tid] = v;
    __syncthreads();
    for (int off = 1; off < SCAN_B; off <<= 1) {
        int y = (tid >= off) ? buf[tid - off] : 0;
        __syncthreads();
        buf[tid] += y;
        __syncthreads();
    }
    if (i < n) part[i] = buf[tid] - v;
    if (tid == SCAN_B - 1) bsum[blockIdx.x] = buf[tid];
}

__global__ __launch_bounds__(128) void scan2_k(int* __restrict__ bsum, int nb) {
    __shared__ int buf[128];
    int tid = threadIdx.x;
    int v = (tid < nb) ? bsum[tid] : 0;
    buf[tid] = v;
    __syncthreads();
    for (int off = 1; off < 128; off <<= 1) {
        int y = (tid >= off) ? buf[tid - off] : 0;
        __syncthreads();
        buf[tid] += y;
        __syncthreads();
    }
    if (tid < nb) bsum[tid] = buf[tid] - v;
    if (tid == nb - 1) bsum[nb] = buf[tid];        // grand total (padded E)
}

__global__ __launch_bounds__(SCAN_B) void scan3_k(int* __restrict__ rowptr,
                                                  const int* __restrict__ bsum,
                                                  int* __restrict__ cursor, int n, int nb) {
    int i = blockIdx.x * SCAN_B + threadIdx.x;
    if (i < n) {
        int v = rowptr[i] + bsum[blockIdx.x];
        rowptr[i] = v;
        cursor[i] = v;
    }
    if (i == 0) rowptr[n] = bsum[nb];
}

__global__ void scatter_k(const int* __restrict__ row, const int* __restrict__ col,
                          const float* __restrict__ val, int* __restrict__ cursor,
                          int2* __restrict__ ecv, int E) {
    int e = blockIdx.x * blockDim.x + threadIdx.x;
    if (e < E) {
        int r = row[e];
        int p = atomicAdd(&cursor[r], 1);
        ecv[p] = make_int2(col[e], __float_as_int(val[e]));
    }
}

// ------- weight prep: W[K][M] f32 -> Bhl[M][2K] bf16, hi8|lo8 groups -------

__global__ void split_w_k(const float* __restrict__ W, short* __restrict__ Bhl,
                          int K, int M) {
    int i = blockIdx.x * 256 + threadIdx.x;
    if (i >= K * M) return;
    int k = i / M, m = i - k * M;
    float x = W[i];
    short hi = bf16_hi(x);
    float r = x - bf16_f32(hi);
    short lo = bf16_hi(r);
    int g = k >> 3, j = k & 7;
    Bhl[(size_t)m * (2 * K) + 16 * g + j] = hi;
    Bhl[(size_t)m * (2 * K) + 16 * g + 8 + j] = lo;
}

// ---------------- 2-phase double-buffered split-MFMA GEMM ------------------
// C[N,BN] = A[N,K] * B[K,BN]. 4 waves as NWR x NWC; wave tile = 64 rows x
// (BN/NWC) cols (m=4, NF frags). LDS rows 128B = 8 16B slots,
// phys_slot = logical_slot ^ (row&7).
// AF32=false: A pre-split interleaved [row][2K], gload w/ pre-swizzled src.
// AF32=true (NWR==1): A f32 [row][K]; prefetch to regs early, convert +
// ds_write late (issue-early/write-late).

template <int K, int BN, int NWR, int NWC, bool AF32>
__global__ __launch_bounds__(256) void gemm_hl(const void* __restrict__ Av,
                                               const short* __restrict__ Bhl,
                                               short* __restrict__ ZQ,
                                               float* __restrict__ scl, int N) {
    constexpr int BM = 64 * NWR;
    constexpr int NF = BN / NWC / 16;
    constexpr int NT = K / 32;
    __shared__ short Ald[2][BM * 64];
    __shared__ short Bld[2][BN * 64];

    const int tid = threadIdx.x, lane = tid & 63, w = tid >> 6;
    const int wr = w / NWC, wc = w % NWC;
    const int row0 = blockIdx.x * BM;
    const int l8 = lane >> 3;                       // row within 8-row chunk
    const int sx = (lane & 7) ^ l8;                 // pre-swizzled source slot

    const short* Ahl = (const short*)Av;
    const float* Af  = (const float*)Av;
    // AF32 staging coords: each thread owns row=tid>>2 (0..63), k-quad q
    const int arow = tid >> 2, aq = tid & 3;
    const int akey = arow & 7;

    f32x4 acc[4][NF] = {};

    auto stageB = [&](int t, int b) {
#pragma unroll
        for (int ch = w; ch < BN / 8; ch += 4)
            gload_lds16(Bhl + (size_t)(ch * 8 + l8) * (2 * K) + (size_t)t * 64 + sx * 8,
                        &Bld[b][ch * 512]);
    };
    auto stageAg = [&](int t, int b) {
#pragma unroll
        for (int ch = w; ch < BM / 8; ch += 4)
            gload_lds16(Ahl + (size_t)(row0 + ch * 8 + l8) * (2 * K) + (size_t)t * 64 + sx * 8,
                        &Ald[b][ch * 512]);
    };
    auto loadAf = [&](int t, float4& x0, float4& x1) {
        int gr = row0 + arow;
        x0 = make_float4(0.f, 0.f, 0.f, 0.f); x1 = x0;
        if (gr < N) {
            x0 = *(const float4*)&Af[(size_t)gr * K + t * 32 + aq * 8];
            x1 = *(const float4*)&Af[(size_t)gr * K + t * 32 + aq * 8 + 4];
        }
    };
    auto writeAf = [&](int b, float4 x0, float4 x1) {
        float f[8] = {x0.x, x0.y, x0.z, x0.w, x1.x, x1.y, x1.z, x1.w};
        short8_t hi, lo;
#pragma unroll
        for (int j = 0; j < 8; ++j) {
            short hh = bf16_hi(f[j]);
            hi[j] = hh;
            lo[j] = bf16_hi(f[j] - bf16_f32(hh));
        }
        *(short8_t*)&Ald[b][arow * 64 + ((2 * aq) ^ akey) * 8] = hi;
        *(short8_t*)&Ald[b][arow * 64 + ((2 * aq + 1) ^ akey) * 8] = lo;
    };

    // ---- prologue: stage tile 0 ----
    if constexpr (AF32) {
        float4 x0, x1;
        loadAf(0, x0, x1);
        writeAf(0, x0, x1);
    } else {
        stageAg(0, 0);
    }
    stageB(0, 0);
    __syncthreads();

    // ---- 2-phase main loop: issue stage(t+1) -> compute(t) -> barrier ----
    for (int t = 0; t < NT; ++t) {
        const int cur = t & 1, nxt = cur ^ 1;
        float4 px0, px1;
        if (t + 1 < NT) {
            if constexpr (AF32) loadAf(t + 1, px0, px1);
            else                stageAg(t + 1, nxt);
            stageB(t + 1, nxt);
        }

        // compute(cur)
        const int sH = (lane >> 4) * 2, sL = sH + 1;
        short8_t ah[4], al[4];
#pragma unroll
        for (int m = 0; m < 4; ++m) {
            int rl = wr * 64 + m * 16 + (lane & 15);
            int key = rl & 7;
            ah[m] = *(const short8_t*)&Ald[cur][rl * 64 + (sH ^ key) * 8];
            al[m] = *(const short8_t*)&Ald[cur][rl * 64 + (sL ^ key) * 8];
        }
#pragma unroll
        for (int n = 0; n < NF; ++n) {
            int cl = wc * (BN / NWC) + n * 16 + (lane & 15);
            int key = cl & 7;
            short8_t bh = *(const short8_t*)&Bld[cur][cl * 64 + (sH ^ key) * 8];
            short8_t bl = *(const short8_t*)&Bld[cur][cl * 64 + (sL ^ key) * 8];
#pragma unroll
            for (int m = 0; m < 4; ++m) {
                acc[m][n] = __builtin_amdgcn_mfma_f32_16x16x32_bf16(ah[m], bh, acc[m][n], 0, 0, 0);
                acc[m][n] = __builtin_amdgcn_mfma_f32_16x16x32_bf16(ah[m], bl, acc[m][n], 0, 0, 0);
                acc[m][n] = __builtin_amdgcn_mfma_f32_16x16x32_bf16(al[m], bh, acc[m][n], 0, 0, 0);
            }
        }
        if constexpr (AF32) {
            if (t + 1 < NT) writeAf(nxt, px0, px1);
        }
        __syncthreads();
    }

    // ---- fused quant epilogue ----
    const int lg = lane >> 4, lc = lane & 15;
    float* maxb = (float*)&Ald[0][0];   // reuse LDS, post-barrier
    float rmax[4][4];
#pragma unroll
    for (int m = 0; m < 4; ++m)
#pragma unroll
        for (int r = 0; r < 4; ++r) {
            float v = 0.f;
#pragma unroll
            for (int n = 0; n < NF; ++n) v = fmaxf(v, fabsf(acc[m][n][r]));
#pragma unroll
            for (int o = 8; o >= 1; o >>= 1) v = fmaxf(v, __shfl_xor(v, o));
            rmax[m][r] = v;
        }
    if constexpr (NWC > 1) {
        if (lc == 0)
#pragma unroll
            for (int m = 0; m < 4; ++m)
#pragma unroll
                for (int r = 0; r < 4; ++r)
                    maxb[(wr * 64 + m * 16 + lg * 4 + r) * NWC + wc] = rmax[m][r];
        __syncthreads();
    }
#pragma unroll
    for (int m = 0; m < 4; ++m)
#pragma unroll
        for (int r = 0; r < 4; ++r) {
            int rl = wr * 64 + m * 16 + lg * 4 + r;
            float v = rmax[m][r];
            if constexpr (NWC > 1) {
                v = maxb[rl * NWC];
#pragma unroll
                for (int q = 1; q < NWC; ++q) v = fmaxf(v, maxb[rl * NWC + q]);
            }
            int grow = row0 + rl;
            if (grow < N) {
                float inv = (v > 0.f) ? 32767.f / v : 0.f;
                if (lc == 0 && wc == 0) scl[grow] = v * (1.f / 32767.f);
#pragma unroll
                for (int n = 0; n < NF; ++n)
                    ZQ[(size_t)grow * BN + wc * (BN / NWC) + n * 16 + lc] =
                        (short)rintf(acc[m][n][r] * inv);
            }
        }
}

// ---------------- SpMM (CSR, padded rows), one wave per dest row -----------

// d=256: 4 gathers of short4 in flight; relu; writes interleaved bf16 hi/lo.
__global__ __launch_bounds__(256) void spmm_agg256_k(const int* __restrict__ rowptr,
                                                     const int2* __restrict__ ecv,
                                                     const short* __restrict__ Q,
                                                     const float* __restrict__ scl,
                                                     short* __restrict__ Zhl, int N) {
    int row = blockIdx.x * 4 + (threadIdx.x >> 6);
    if (row >= N) return;
    int lane = threadIdx.x & 63;
    int s = rowptr[row], e = rowptr[row + 1];   // both %4
    const short4_t* Qv = (const short4_t*)Q;
    f32x4 acc = {0.f, 0.f, 0.f, 0.f};
    for (int i = s; i < e; i += 4) {
        int4 a = *(const int4*)(ecv + i);
        int4 b = *(const int4*)(ecv + i + 2);
        float w0 = __int_as_float(a.y) * scl[a.x];
        float w1 = __int_as_float(a.w) * scl[a.z];
        float w2 = __int_as_float(b.y) * scl[b.x];
        float w3 = __int_as_float(b.w) * scl[b.z];
        short4_t q0 = Qv[(size_t)a.x * 64 + lane];
        short4_t q1 = Qv[(size_t)a.z * 64 + lane];
        short4_t q2 = Qv[(size_t)b.x * 64 + lane];
        short4_t q3 = Qv[(size_t)b.z * 64 + lane];
#pragma unroll
        for (int j = 0; j < 4; ++j) {
            acc[j] = fmaf(w0, (float)q0[j], acc[j]);
            acc[j] = fmaf(w1, (float)q1[j], acc[j]);
            acc[j] = fmaf(w2, (float)q2[j], acc[j]);
            acc[j] = fmaf(w3, (float)q3[j], acc[j]);
        }
    }
    // relu + hi/lo split, interleaved layout: group g = lane>>1, half = lane&1
    short4_t hi, lo;
#pragma unroll
    for (int j = 0; j < 4; ++j) {
        float r = fmaxf(acc[j], 0.f);
        short h = bf16_hi(r);
        hi[j] = h;
        lo[j] = bf16_hi(r - bf16_f32(h));
    }
    size_t base = (size_t)row * 512 + (lane >> 1) * 16 + (lane & 1) * 4;
    *(short4_t*)&Zhl[base] = hi;
    *(short4_t*)&Zhl[base + 8] = lo;
}

// d=64: 4 gathers of short in flight; fused row softmax.
__global__ __launch_bounds__(256) void spmm_softmax64_k(const int* __restrict__ rowptr,
                                                        const int2* __restrict__ ecv,
                                                        const short* __restrict__ Q,
                                                        const float* __restrict__ scl,
                                                        float* __restrict__ out, int N) {
    int row = blockIdx.x * 4 + (threadIdx.x >> 6);
    if (row >= N) return;
    int lane = threadIdx.x & 63;
    int s = rowptr[row], e = rowptr[row + 1];
    float acc = 0.f;
    for (int i = s; i < e; i += 4) {
        int4 a = *(const int4*)(ecv + i);
        int4 b = *(const int4*)(ecv + i + 2);
        float w0 = __int_as_float(a.y) * scl[a.x];
        float w1 = __int_as_float(a.w) * scl[a.z];
        float w2 = __int_as_float(b.y) * scl[b.x];
        float w3 = __int_as_float(b.w) * scl[b.z];
        float z0 = (float)Q[(size_t)a.x * 64 + lane];
        float z1 = (float)Q[(size_t)a.z * 64 + lane];
        float z2 = (float)Q[(size_t)b.x * 64 + lane];
        float z3 = (float)Q[(size_t)b.z * 64 + lane];
        acc = fmaf(w0, z0, acc);
        acc = fmaf(w1, z1, acc);
        acc = fmaf(w2, z2, acc);
        acc = fmaf(w3, z3, acc);
    }
    float m = acc;
#pragma unroll
    for (int o = 32; o >= 1; o >>= 1) m = fmaxf(m, __shfl_xor(m, o));
    float p = __expf(acc - m);
    float ssum = p;
#pragma unroll
    for (int o = 32; o >= 1; o >>= 1) ssum += __shfl_xor(ssum, o);
    out[(size_t)row * 64 + lane] = p / ssum;
}

// ---------------------------------------------------------------------------

extern "C" void kernel_launch(void* const* d_in, const int* in_sizes, int n_in,
                              void* d_out, int out_size, void* d_ws, size_t ws_size,
                              hipStream_t stream) {
    const float* X        = (const float*)d_in[0];
    const int*   edge_row = (const int*)d_in[1];
    const int*   edge_col = (const int*)d_in[2];
    const float* edge_val = (const float*)d_in[3];
    const float* W0       = (const float*)d_in[4];
    const float* Wh1      = (const float*)d_in[5];
    const float* W1       = (const float*)d_in[6];

    const int C = 512, H = 256, F = 64;
    const int N = in_sizes[0] / C;     // 100000
    const int E = in_sizes[1];         // 3200000
    const int EPAD = E + 4 * N + 64;   // padded-edge capacity

    size_t off = 0;
    auto alloc = [&](size_t bytes) -> void* {
        void* p = (char*)d_ws + off;
        off += (bytes + 255) & ~(size_t)255;
        return p;
    };
    // Zhl first: gemm_hl gload-A overreads it by <=127 rows (~127KB);
    // ZQ follows as slack.
    short* Zhl    = (short*)alloc((size_t)N * 2 * H * sizeof(short));  // 102.4MB
    short* ZQ     = (short*)alloc((size_t)N * H * sizeof(short));      // 51.2MB
    float* scl    = (float*)alloc((size_t)N * sizeof(float));
    int*   deg    = (int*)alloc((size_t)N * sizeof(int));
    int*   rowptr = (int*)alloc((size_t)(N + 1) * sizeof(int));
    int*   cursor = (int*)alloc((size_t)N * sizeof(int));
    int*   bsum   = (int*)alloc(129 * sizeof(int));
    int2*  ecv    = (int2*)alloc((size_t)EPAD * sizeof(int2));
    short* Bhl0   = (short*)alloc((size_t)H * 2 * C * sizeof(short));  // [256][1024]
    short* Bhl1   = (short*)alloc((size_t)H * 2 * H * sizeof(short));  // [256][512]
    short* Bhl2   = (short*)alloc((size_t)F * 2 * H * sizeof(short));  // [64][512]
    (void)ws_size;

    // ---- build padded CSR ----
    hipMemsetAsync(deg, 0, (size_t)N * sizeof(int), stream);
    hipMemsetAsync(ecv, 0, (size_t)EPAD * sizeof(int2), stream);
    count_rows_k<<<(E + 255) / 256, 256, 0, stream>>>(edge_row, deg, E);
    int nb = (N + SCAN_B - 1) / SCAN_B;          // 98 <= 128
    scan1_k<<<nb, SCAN_B, 0, stream>>>(deg, rowptr, bsum, N);
    scan2_k<<<1, 128, 0, stream>>>(bsum, nb);
    scan3_k<<<nb, SCAN_B, 0, stream>>>(rowptr, bsum, cursor, N, nb);
    scatter_k<<<(E + 255) / 256, 256, 0, stream>>>(edge_row, edge_col, edge_val,
                                                   cursor, ecv, E);

    // ---- prep weights ----
    split_w_k<<<(C * H + 255) / 256, 256, 0, stream>>>(W0, Bhl0, C, H);
    split_w_k<<<(H * H + 255) / 256, 256, 0, stream>>>(Wh1, Bhl1, H, H);
    split_w_k<<<(H * F + 255) / 256, 256, 0, stream>>>(W1, Bhl2, H, F);

    const int g64  = (N + 63) / 64;              // 1563
    const int g128 = (N + 127) / 128;            // 782
    const int rg   = (N + 3) / 4;                // 25000

    // ---- layer 0 ----
    gemm_hl<512, 256, 1, 4, true><<<g64, 256, 0, stream>>>(X, Bhl0, ZQ, scl, N);
    spmm_agg256_k<<<rg, 256, 0, stream>>>(rowptr, ecv, ZQ, scl, Zhl, N);
    // ---- layer 1 ----
    gemm_hl<256, 256, 1, 4, false><<<g64, 256, 0, stream>>>(Zhl, Bhl1, ZQ, scl, N);
    spmm_agg256_k<<<rg, 256, 0, stream>>>(rowptr, ecv, ZQ, scl, Zhl, N);
    // ---- layer 2 ----
    gemm_hl<256, 64, 2, 2, false><<<g128, 256, 0, stream>>>(Zhl, Bhl2, ZQ, scl, N);
    spmm_softmax64_k<<<rg, 256, 0, stream>>>(rowptr, ecv, ZQ, scl,
                                             (float*)d_out, N);
}

// Round 8
// 1124.187 us; speedup vs baseline: 1.0393x; 1.0393x over previous
//
#include <hip/hip_runtime.h>
#include <cstdint>
#include <cstddef>

// ---------------------------------------------------------------------------
// GCN forward. CSR built on-device (rows padded %4, packed (col,val) pairs).
// Scatter is XCD-partitioned: 8 row-groups, each written by blocks whose
// (blockIdx%8) matches -> one XCD owns each destination line (kills the 8x
// dirty-line amplification measured in round 7). SpMM gathers per-row
// int16-quantized rows with wide (16B/8B) lane loads, accumulates f32,
// writes interleaved bf16 hi/lo planes (Zhl) = next GEMM's A operand.
// GEMM: 2-phase double-buffered 3-term split-MFMA (unchanged from round 7).
// ---------------------------------------------------------------------------

#define SCAN_B 1024

typedef __attribute__((ext_vector_type(8))) short short8_t;
typedef __attribute__((ext_vector_type(4))) short short4_t;
typedef __attribute__((ext_vector_type(4))) float f32x4;

__device__ __forceinline__ short bf16_hi(float x) {
    union { float f; unsigned u; } c; c.f = x;
    return (short)(c.u >> 16);
}
__device__ __forceinline__ float bf16_f32(short h) {
    union { float f; unsigned u; } c; c.u = ((unsigned)(unsigned short)h) << 16;
    return c.f;
}

__device__ __forceinline__ void gload_lds16(const void* g, void* l) {
    __builtin_amdgcn_global_load_lds(
        (const __attribute__((address_space(1))) void*)g,
        (__attribute__((address_space(3))) void*)l, 16, 0, 0);
}

// ---------------- CSR construction (rows padded to %4) ----------------

__global__ void count_rows_k(const int* __restrict__ row, int* __restrict__ deg, int E) {
    int e = blockIdx.x * blockDim.x + threadIdx.x;
    if (e < E) atomicAdd(&deg[row[e]], 1);
}

__global__ __launch_bounds__(SCAN_B) void scan1_k(const int* __restrict__ deg,
                                                  int* __restrict__ part,
                                                  int* __restrict__ bsum, int n) {
    __shared__ int buf[SCAN_B];
    int tid = threadIdx.x;
    int i = blockIdx.x * SCAN_B + tid;
    int v = (i < n) ? ((deg[i] + 3) & ~3) : 0;     // padded degree
    buf[tid] = v;
    __syncthreads();
    for (int off = 1; off < SCAN_B; off <<= 1) {
        int y = (tid >= off) ? buf[tid - off] : 0;
        __syncthreads();
        buf[tid] += y;
        __syncthreads();
    }
    if (i < n) part[i] = buf[tid] - v;
    if (tid == SCAN_B - 1) bsum[blockIdx.x] = buf[tid];
}

__global__ __launch_bounds__(128) void scan2_k(int* __restrict__ bsum, int nb) {
    __shared__ int buf[128];
    int tid = threadIdx.x;
    int v = (tid < nb) ? bsum[tid] : 0;
    buf[tid] = v;
    __syncthreads();
    for (int off = 1; off < 128; off <<= 1) {
        int y = (tid >= off) ? buf[tid - off] : 0;
        __syncthreads();
        buf[tid] += y;
        __syncthreads();
    }
    if (tid < nb) bsum[tid] = buf[tid] - v;
    if (tid == nb - 1) bsum[nb] = buf[tid];        // grand total (padded E)
}

__global__ __launch_bounds__(SCAN_B) void scan3_k(int* __restrict__ rowptr,
                                                  const int* __restrict__ bsum,
                                                  int* __restrict__ cursor, int n, int nb) {
    int i = blockIdx.x * SCAN_B + threadIdx.x;
    if (i < n) {
        int v = rowptr[i] + bsum[blockIdx.x];
        rowptr[i] = v;
        cursor[i] = v;
    }
    if (i == 0) rowptr[n] = bsum[nb];
}

// XCD-partitioned scatter: group g = blockIdx&7 handles rows [g*gsz,(g+1)*gsz).
// Every group streams ALL edges (coalesced; row/col/val become L3-resident),
// but writes land only in its own slice -> single-XCD line ownership.
__global__ __launch_bounds__(256) void scatter_xcd_k(const int* __restrict__ row,
                                                     const int* __restrict__ col,
                                                     const float* __restrict__ val,
                                                     int* __restrict__ cursor,
                                                     int2* __restrict__ ecv,
                                                     int E, int gsz) {
    const int g = blockIdx.x & 7;
    const int rank = blockIdx.x >> 3;
    const int R = gridDim.x >> 3;
    const int lo = g * gsz, hi = lo + gsz;
    for (int e = rank * 256 + threadIdx.x; e < E; e += R * 256) {
        int r = row[e];
        if (r >= lo && r < hi) {
            int p = atomicAdd(&cursor[r], 1);
            ecv[p] = make_int2(col[e], __float_as_int(val[e]));
        }
    }
}

// ------- weight prep: W[K][M] f32 -> Bhl[M][2K] bf16, hi8|lo8 groups -------

__global__ void split_w_k(const float* __restrict__ W, short* __restrict__ Bhl,
                          int K, int M) {
    int i = blockIdx.x * 256 + threadIdx.x;
    if (i >= K * M) return;
    int k = i / M, m = i - k * M;
    float x = W[i];
    short hi = bf16_hi(x);
    float r = x - bf16_f32(hi);
    short lo = bf16_hi(r);
    int g = k >> 3, j = k & 7;
    Bhl[(size_t)m * (2 * K) + 16 * g + j] = hi;
    Bhl[(size_t)m * (2 * K) + 16 * g + 8 + j] = lo;
}

// ---------------- 2-phase double-buffered split-MFMA GEMM ------------------

template <int K, int BN, int NWR, int NWC, bool AF32>
__global__ __launch_bounds__(256) void gemm_hl(const void* __restrict__ Av,
                                               const short* __restrict__ Bhl,
                                               short* __restrict__ ZQ,
                                               float* __restrict__ scl, int N) {
    constexpr int BM = 64 * NWR;
    constexpr int NF = BN / NWC / 16;
    constexpr int NT = K / 32;
    __shared__ short Ald[2][BM * 64];
    __shared__ short Bld[2][BN * 64];

    const int tid = threadIdx.x, lane = tid & 63, w = tid >> 6;
    const int wr = w / NWC, wc = w % NWC;
    const int row0 = blockIdx.x * BM;
    const int l8 = lane >> 3;
    const int sx = (lane & 7) ^ l8;

    const short* Ahl = (const short*)Av;
    const float* Af  = (const float*)Av;
    const int arow = tid >> 2, aq = tid & 3;
    const int akey = arow & 7;

    f32x4 acc[4][NF] = {};

    auto stageB = [&](int t, int b) {
#pragma unroll
        for (int ch = w; ch < BN / 8; ch += 4)
            gload_lds16(Bhl + (size_t)(ch * 8 + l8) * (2 * K) + (size_t)t * 64 + sx * 8,
                        &Bld[b][ch * 512]);
    };
    auto stageAg = [&](int t, int b) {
#pragma unroll
        for (int ch = w; ch < BM / 8; ch += 4)
            gload_lds16(Ahl + (size_t)(row0 + ch * 8 + l8) * (2 * K) + (size_t)t * 64 + sx * 8,
                        &Ald[b][ch * 512]);
    };
    auto loadAf = [&](int t, float4& x0, float4& x1) {
        int gr = row0 + arow;
        x0 = make_float4(0.f, 0.f, 0.f, 0.f); x1 = x0;
        if (gr < N) {
            x0 = *(const float4*)&Af[(size_t)gr * K + t * 32 + aq * 8];
            x1 = *(const float4*)&Af[(size_t)gr * K + t * 32 + aq * 8 + 4];
        }
    };
    auto writeAf = [&](int b, float4 x0, float4 x1) {
        float f[8] = {x0.x, x0.y, x0.z, x0.w, x1.x, x1.y, x1.z, x1.w};
        short8_t hi, lo;
#pragma unroll
        for (int j = 0; j < 8; ++j) {
            short hh = bf16_hi(f[j]);
            hi[j] = hh;
            lo[j] = bf16_hi(f[j] - bf16_f32(hh));
        }
        *(short8_t*)&Ald[b][arow * 64 + ((2 * aq) ^ akey) * 8] = hi;
        *(short8_t*)&Ald[b][arow * 64 + ((2 * aq + 1) ^ akey) * 8] = lo;
    };

    if constexpr (AF32) {
        float4 x0, x1;
        loadAf(0, x0, x1);
        writeAf(0, x0, x1);
    } else {
        stageAg(0, 0);
    }
    stageB(0, 0);
    __syncthreads();

    for (int t = 0; t < NT; ++t) {
        const int cur = t & 1, nxt = cur ^ 1;
        float4 px0, px1;
        if (t + 1 < NT) {
            if constexpr (AF32) loadAf(t + 1, px0, px1);
            else                stageAg(t + 1, nxt);
            stageB(t + 1, nxt);
        }

        const int sH = (lane >> 4) * 2, sL = sH + 1;
        short8_t ah[4], al[4];
#pragma unroll
        for (int m = 0; m < 4; ++m) {
            int rl = wr * 64 + m * 16 + (lane & 15);
            int key = rl & 7;
            ah[m] = *(const short8_t*)&Ald[cur][rl * 64 + (sH ^ key) * 8];
            al[m] = *(const short8_t*)&Ald[cur][rl * 64 + (sL ^ key) * 8];
        }
#pragma unroll
        for (int n = 0; n < NF; ++n) {
            int cl = wc * (BN / NWC) + n * 16 + (lane & 15);
            int key = cl & 7;
            short8_t bh = *(const short8_t*)&Bld[cur][cl * 64 + (sH ^ key) * 8];
            short8_t bl = *(const short8_t*)&Bld[cur][cl * 64 + (sL ^ key) * 8];
#pragma unroll
            for (int m = 0; m < 4; ++m) {
                acc[m][n] = __builtin_amdgcn_mfma_f32_16x16x32_bf16(ah[m], bh, acc[m][n], 0, 0, 0);
                acc[m][n] = __builtin_amdgcn_mfma_f32_16x16x32_bf16(ah[m], bl, acc[m][n], 0, 0, 0);
                acc[m][n] = __builtin_amdgcn_mfma_f32_16x16x32_bf16(al[m], bh, acc[m][n], 0, 0, 0);
            }
        }
        if constexpr (AF32) {
            if (t + 1 < NT) writeAf(nxt, px0, px1);
        }
        __syncthreads();
    }

    // ---- fused quant epilogue ----
    const int lg = lane >> 4, lc = lane & 15;
    float* maxb = (float*)&Ald[0][0];
    float rmax[4][4];
#pragma unroll
    for (int m = 0; m < 4; ++m)
#pragma unroll
        for (int r = 0; r < 4; ++r) {
            float v = 0.f;
#pragma unroll
            for (int n = 0; n < NF; ++n) v = fmaxf(v, fabsf(acc[m][n][r]));
#pragma unroll
            for (int o = 8; o >= 1; o >>= 1) v = fmaxf(v, __shfl_xor(v, o));
            rmax[m][r] = v;
        }
    if constexpr (NWC > 1) {
        if (lc == 0)
#pragma unroll
            for (int m = 0; m < 4; ++m)
#pragma unroll
                for (int r = 0; r < 4; ++r)
                    maxb[(wr * 64 + m * 16 + lg * 4 + r) * NWC + wc] = rmax[m][r];
        __syncthreads();
    }
#pragma unroll
    for (int m = 0; m < 4; ++m)
#pragma unroll
        for (int r = 0; r < 4; ++r) {
            int rl = wr * 64 + m * 16 + lg * 4 + r;
            float v = rmax[m][r];
            if constexpr (NWC > 1) {
                v = maxb[rl * NWC];
#pragma unroll
                for (int q = 1; q < NWC; ++q) v = fmaxf(v, maxb[rl * NWC + q]);
            }
            int grow = row0 + rl;
            if (grow < N) {
                float inv = (v > 0.f) ? 32767.f / v : 0.f;
                if (lc == 0 && wc == 0) scl[grow] = v * (1.f / 32767.f);
#pragma unroll
                for (int n = 0; n < NF; ++n)
                    ZQ[(size_t)grow * BN + wc * (BN / NWC) + n * 16 + lc] =
                        (short)rintf(acc[m][n][r] * inv);
            }
        }
}

// ---------------- SpMM (CSR, padded rows), one wave per dest row -----------

// d=256, wide: lane loads short8 (16B); half h of wave covers edge 2i+h.
// 2 VMEM gathers per 4 edges (was 4). Cross-half combine via shfl_xor(32).
__global__ __launch_bounds__(256) void spmm_agg256_k(const int* __restrict__ rowptr,
                                                     const int2* __restrict__ ecv,
                                                     const short* __restrict__ Q,
                                                     const float* __restrict__ scl,
                                                     short* __restrict__ Zhl, int N) {
    int row = blockIdx.x * 4 + (threadIdx.x >> 6);
    if (row >= N) return;
    const int lane = threadIdx.x & 63;
    const int half = lane >> 5;
    const int l32 = lane & 31;              // 16B chunk = channels [l32*8, +8)
    int s = rowptr[row], e = rowptr[row + 1];   // both %4
    const short8_t* Qv = (const short8_t*)Q;    // row = 32 chunks
    f32x4 a0 = {0.f, 0.f, 0.f, 0.f}, a1 = a0;
    for (int i = s; i < e; i += 4) {
        int4 A = *(const int4*)(ecv + i);        // edges i, i+1
        int4 B = *(const int4*)(ecv + i + 2);    // edges i+2, i+3
        int   cA = half ? A.z : A.x;
        float wA = __int_as_float(half ? A.w : A.y) * scl[cA];
        int   cB = half ? B.z : B.x;
        float wB = __int_as_float(half ? B.w : B.y) * scl[cB];
        short8_t qA = Qv[(size_t)cA * 32 + l32];
        short8_t qB = Qv[(size_t)cB * 32 + l32];
#pragma unroll
        for (int j = 0; j < 4; ++j) {
            a0[j] = fmaf(wA, (float)qA[j], a0[j]);
            a1[j] = fmaf(wA, (float)qA[j + 4], a1[j]);
            a0[j] = fmaf(wB, (float)qB[j], a0[j]);
            a1[j] = fmaf(wB, (float)qB[j + 4], a1[j]);
        }
    }
    // combine halves (each half summed a disjoint set of edges)
#pragma unroll
    for (int j = 0; j < 4; ++j) {
        a0[j] += __shfl_xor(a0[j], 32);
        a1[j] += __shfl_xor(a1[j], 32);
    }
    if (half == 0) {
        // relu + hi/lo split; Zhl layout: group g=l32 -> [16g..16g+8)=hi, +8=lo
        short8_t hi, lo;
#pragma unroll
        for (int j = 0; j < 4; ++j) {
            float r0 = fmaxf(a0[j], 0.f), r1 = fmaxf(a1[j], 0.f);
            short h0 = bf16_hi(r0), h1 = bf16_hi(r1);
            hi[j] = h0; hi[j + 4] = h1;
            lo[j] = bf16_hi(r0 - bf16_f32(h0));
            lo[j + 4] = bf16_hi(r1 - bf16_f32(h1));
        }
        size_t base = (size_t)row * 512 + l32 * 16;
        *(short8_t*)&Zhl[base] = hi;
        *(short8_t*)&Zhl[base + 8] = lo;
    }
}

// d=64, wide: lane loads short4 (8B); quarter q covers edge 4i+q.
// 1 VMEM gather per 4 edges (was 4). Combine via shfl_xor(16),(32).
__global__ __launch_bounds__(256) void spmm_softmax64_k(const int* __restrict__ rowptr,
                                                        const int2* __restrict__ ecv,
                                                        const short* __restrict__ Q,
                                                        const float* __restrict__ scl,
                                                        float* __restrict__ out, int N) {
    int row = blockIdx.x * 4 + (threadIdx.x >> 6);
    if (row >= N) return;
    const int lane = threadIdx.x & 63;
    const int q = lane >> 4;                // edge-slot 0..3
    const int l16 = lane & 15;              // channels [l16*4, +4)
    int s = rowptr[row], e = rowptr[row + 1];
    const short4_t* Qv = (const short4_t*)Q;    // row = 16 chunks of 8B
    f32x4 acc = {0.f, 0.f, 0.f, 0.f};
    for (int i = s; i < e; i += 4) {
        int4 A = *(const int4*)(ecv + i);
        int4 B = *(const int4*)(ecv + i + 2);
        int c = (q & 2) ? ((q & 1) ? B.z : B.x) : ((q & 1) ? A.z : A.x);
        int wbits = (q & 2) ? ((q & 1) ? B.w : B.y) : ((q & 1) ? A.w : A.y);
        float wv = __int_as_float(wbits) * scl[c];
        short4_t z = Qv[(size_t)c * 16 + l16];
#pragma unroll
        for (int j = 0; j < 4; ++j) acc[j] = fmaf(wv, (float)z[j], acc[j]);
    }
#pragma unroll
    for (int j = 0; j < 4; ++j) {
        acc[j] += __shfl_xor(acc[j], 16);
        acc[j] += __shfl_xor(acc[j], 32);
    }
    // row softmax over 64 channels distributed as 16 lanes x 4
    float m = fmaxf(fmaxf(acc[0], acc[1]), fmaxf(acc[2], acc[3]));
#pragma unroll
    for (int o = 8; o >= 1; o >>= 1) m = fmaxf(m, __shfl_xor(m, o));
    float p0 = __expf(acc[0] - m), p1 = __expf(acc[1] - m);
    float p2 = __expf(acc[2] - m), p3 = __expf(acc[3] - m);
    float ssum = p0 + p1 + p2 + p3;
#pragma unroll
    for (int o = 8; o >= 1; o >>= 1) ssum += __shfl_xor(ssum, o);
    if (q == 0) {
        float inv = 1.f / ssum;
        float4 o4 = make_float4(p0 * inv, p1 * inv, p2 * inv, p3 * inv);
        *(float4*)&out[(size_t)row * 64 + l16 * 4] = o4;
    }
}

// ---------------------------------------------------------------------------

extern "C" void kernel_launch(void* const* d_in, const int* in_sizes, int n_in,
                              void* d_out, int out_size, void* d_ws, size_t ws_size,
                              hipStream_t stream) {
    const float* X        = (const float*)d_in[0];
    const int*   edge_row = (const int*)d_in[1];
    const int*   edge_col = (const int*)d_in[2];
    const float* edge_val = (const float*)d_in[3];
    const float* W0       = (const float*)d_in[4];
    const float* Wh1      = (const float*)d_in[5];
    const float* W1       = (const float*)d_in[6];

    const int C = 512, H = 256, F = 64;
    const int N = in_sizes[0] / C;     // 100000
    const int E = in_sizes[1];         // 3200000
    const int EPAD = E + 4 * N + 64;   // padded-edge capacity

    size_t off = 0;
    auto alloc = [&](size_t bytes) -> void* {
        void* p = (char*)d_ws + off;
        off += (bytes + 255) & ~(size_t)255;
        return p;
    };
    short* Zhl    = (short*)alloc((size_t)N * 2 * H * sizeof(short));  // 102.4MB
    short* ZQ     = (short*)alloc((size_t)N * H * sizeof(short));      // 51.2MB
    float* scl    = (float*)alloc((size_t)N * sizeof(float));
    int*   deg    = (int*)alloc((size_t)N * sizeof(int));
    int*   rowptr = (int*)alloc((size_t)(N + 1) * sizeof(int));
    int*   cursor = (int*)alloc((size_t)N * sizeof(int));
    int*   bsum   = (int*)alloc(129 * sizeof(int));
    int2*  ecv    = (int2*)alloc((size_t)EPAD * sizeof(int2));
    short* Bhl0   = (short*)alloc((size_t)H * 2 * C * sizeof(short));  // [256][1024]
    short* Bhl1   = (short*)alloc((size_t)H * 2 * H * sizeof(short));  // [256][512]
    short* Bhl2   = (short*)alloc((size_t)F * 2 * H * sizeof(short));  // [64][512]
    (void)ws_size;

    // ---- build padded CSR ----
    hipMemsetAsync(deg, 0, (size_t)N * sizeof(int), stream);
    hipMemsetAsync(ecv, 0, (size_t)EPAD * sizeof(int2), stream);
    count_rows_k<<<(E + 255) / 256, 256, 0, stream>>>(edge_row, deg, E);
    int nb = (N + SCAN_B - 1) / SCAN_B;          // 98 <= 128
    scan1_k<<<nb, SCAN_B, 0, stream>>>(deg, rowptr, bsum, N);
    scan2_k<<<1, 128, 0, stream>>>(bsum, nb);
    scan3_k<<<nb, SCAN_B, 0, stream>>>(rowptr, bsum, cursor, N, nb);
    const int gsz = (N + 7) / 8;                 // 12500 rows per XCD group
    scatter_xcd_k<<<8 * 256, 256, 0, stream>>>(edge_row, edge_col, edge_val,
                                               cursor, ecv, E, gsz);

    // ---- prep weights ----
    split_w_k<<<(C * H + 255) / 256, 256, 0, stream>>>(W0, Bhl0, C, H);
    split_w_k<<<(H * H + 255) / 256, 256, 0, stream>>>(Wh1, Bhl1, H, H);
    split_w_k<<<(H * F + 255) / 256, 256, 0, stream>>>(W1, Bhl2, H, F);

    const int g64  = (N + 63) / 64;              // 1563
    const int g128 = (N + 127) / 128;            // 782
    const int rg   = (N + 3) / 4;                // 25000

    // ---- layer 0 ----
    gemm_hl<512, 256, 1, 4, true><<<g64, 256, 0, stream>>>(X, Bhl0, ZQ, scl, N);
    spmm_agg256_k<<<rg, 256, 0, stream>>>(rowptr, ecv, ZQ, scl, Zhl, N);
    // ---- layer 1 ----
    gemm_hl<256, 256, 1, 4, false><<<g64, 256, 0, stream>>>(Zhl, Bhl1, ZQ, scl, N);
    spmm_agg256_k<<<rg, 256, 0, stream>>>(rowptr, ecv, ZQ, scl, Zhl, N);
    // ---- layer 2 ----
    gemm_hl<256, 64, 2, 2, false><<<g128, 256, 0, stream>>>(Zhl, Bhl2, ZQ, scl, N);
    spmm_softmax64_k<<<rg, 256, 0, stream>>>(rowptr, ecv, ZQ, scl,
                                             (float*)d_out, N);
}

// Round 9
// 1122.149 us; speedup vs baseline: 1.0412x; 1.0018x over previous
//
#include <hip/hip_runtime.h>
#include <cstdint>
#include <cstddef>

// ---------------------------------------------------------------------------
// GCN forward. CSR built on-device (rows padded %4, packed (col,val) pairs,
// XCD-partitioned scatter). SpMM gathers per-row int16-quantized rows (wide
// lane loads), accumulates f32, writes interleaved bf16 hi/lo planes (Zhl).
// GEMM: 3-term split-MFMA, XOR-8 swizzled LDS, ROUND 9: counted-vmcnt +
// raw s_barrier 2-deep pipeline — stage(t+2) loads stay in flight ACROSS the
// barrier (only t+1's are drained), instead of __syncthreads' vmcnt(0) drain.
// Fused per-row int16 quantization epilogue.
// ---------------------------------------------------------------------------

#define SCAN_B 1024

typedef __attribute__((ext_vector_type(8))) short short8_t;
typedef __attribute__((ext_vector_type(4))) short short4_t;
typedef __attribute__((ext_vector_type(4))) float f32x4;

__device__ __forceinline__ short bf16_hi(float x) {
    union { float f; unsigned u; } c; c.f = x;
    return (short)(c.u >> 16);
}
__device__ __forceinline__ float bf16_f32(short h) {
    union { float f; unsigned u; } c; c.u = ((unsigned)(unsigned short)h) << 16;
    return c.f;
}

__device__ __forceinline__ void gload_lds16(const void* g, void* l) {
    __builtin_amdgcn_global_load_lds(
        (const __attribute__((address_space(1))) void*)g,
        (__attribute__((address_space(3))) void*)l, 16, 0, 0);
}

#define GBAR() asm volatile("s_barrier" ::: "memory")
#define LGKM0() asm volatile("s_waitcnt lgkmcnt(0)" ::: "memory")

// counted vmcnt wait; n is compile-time-foldable after unroll
__device__ __forceinline__ void wait_vm(int n) {
    switch (n) {
        case 0:  asm volatile("s_waitcnt vmcnt(0)"  ::: "memory"); break;
        case 6:  asm volatile("s_waitcnt vmcnt(6)"  ::: "memory"); break;
        case 8:  asm volatile("s_waitcnt vmcnt(8)"  ::: "memory"); break;
        default: asm volatile("s_waitcnt vmcnt(10)" ::: "memory"); break;
    }
}

// ---------------- CSR construction (rows padded to %4) ----------------

__global__ void count_rows_k(const int* __restrict__ row, int* __restrict__ deg, int E) {
    int e = blockIdx.x * blockDim.x + threadIdx.x;
    if (e < E) atomicAdd(&deg[row[e]], 1);
}

__global__ __launch_bounds__(SCAN_B) void scan1_k(const int* __restrict__ deg,
                                                  int* __restrict__ part,
                                                  int* __restrict__ bsum, int n) {
    __shared__ int buf[SCAN_B];
    int tid = threadIdx.x;
    int i = blockIdx.x * SCAN_B + tid;
    int v = (i < n) ? ((deg[i] + 3) & ~3) : 0;     // padded degree
    buf[tid] = v;
    __syncthreads();
    for (int off = 1; off < SCAN_B; off <<= 1) {
        int y = (tid >= off) ? buf[tid - off] : 0;
        __syncthreads();
        buf[tid] += y;
        __syncthreads();
    }
    if (i < n) part[i] = buf[tid] - v;
    if (tid == SCAN_B - 1) bsum[blockIdx.x] = buf[tid];
}

__global__ __launch_bounds__(128) void scan2_k(int* __restrict__ bsum, int nb) {
    __shared__ int buf[128];
    int tid = threadIdx.x;
    int v = (tid < nb) ? bsum[tid] : 0;
    buf[tid] = v;
    __syncthreads();
    for (int off = 1; off < 128; off <<= 1) {
        int y = (tid >= off) ? buf[tid - off] : 0;
        __syncthreads();
        buf[tid] += y;
        __syncthreads();
    }
    if (tid < nb) bsum[tid] = buf[tid] - v;
    if (tid == nb - 1) bsum[nb] = buf[tid];        // grand total (padded E)
}

__global__ __launch_bounds__(SCAN_B) void scan3_k(int* __restrict__ rowptr,
                                                  const int* __restrict__ bsum,
                                                  int* __restrict__ cursor, int n, int nb) {
    int i = blockIdx.x * SCAN_B + threadIdx.x;
    if (i < n) {
        int v = rowptr[i] + bsum[blockIdx.x];
        rowptr[i] = v;
        cursor[i] = v;
    }
    if (i == 0) rowptr[n] = bsum[nb];
}

// XCD-partitioned scatter: group g = blockIdx&7 owns rows [g*gsz,(g+1)*gsz).
__global__ __launch_bounds__(256) void scatter_xcd_k(const int* __restrict__ row,
                                                     const int* __restrict__ col,
                                                     const float* __restrict__ val,
                                                     int* __restrict__ cursor,
                                                     int2* __restrict__ ecv,
                                                     int E, int gsz) {
    const int g = blockIdx.x & 7;
    const int rank = blockIdx.x >> 3;
    const int R = gridDim.x >> 3;
    const int lo = g * gsz, hi = lo + gsz;
    for (int e = rank * 256 + threadIdx.x; e < E; e += R * 256) {
        int r = row[e];
        if (r >= lo && r < hi) {
            int p = atomicAdd(&cursor[r], 1);
            ecv[p] = make_int2(col[e], __float_as_int(val[e]));
        }
    }
}

// ------- weight prep: W[K][M] f32 -> Bhl[M][2K] bf16, hi8|lo8 groups -------

__global__ void split_w_k(const float* __restrict__ W, short* __restrict__ Bhl,
                          int K, int M) {
    int i = blockIdx.x * 256 + threadIdx.x;
    if (i >= K * M) return;
    int k = i / M, m = i - k * M;
    float x = W[i];
    short hi = bf16_hi(x);
    float r = x - bf16_f32(hi);
    short lo = bf16_hi(r);
    int g = k >> 3, j = k & 7;
    Bhl[(size_t)m * (2 * K) + 16 * g + j] = hi;
    Bhl[(size_t)m * (2 * K) + 16 * g + 8 + j] = lo;
}

// ---------------- counted-vmcnt pipelined split-MFMA GEMM ------------------
// C[N,BN] = A[N,K] * B[K,BN]. 4 waves as NWR x NWC; wave tile = 64 rows x
// (BN/NWC) cols. LDS rows 128B = 8 16B slots, phys = logical ^ (row&7).
// Pipeline: 2 LDS buffers, 2 tiles in flight; per iter only tile-(t+1)'s
// loads are drained (vmcnt(L)); tile-(t+2)'s cross the barrier in flight.

template <int K, int BN, int NWR, int NWC, bool AF32>
__global__ __launch_bounds__(256) void gemm_hl(const void* __restrict__ Av,
                                               const short* __restrict__ Bhl,
                                               short* __restrict__ ZQ,
                                               float* __restrict__ scl, int N) {
    constexpr int BM = 64 * NWR;
    constexpr int NF = BN / NWC / 16;
    constexpr int NT = K / 32;
    constexpr int LB = BN / 8 / 4;                // B gloads per wave per stage
    constexpr int LA = AF32 ? 0 : BM / 8 / 4;     // A gloads per wave per stage
    constexpr int L  = LA + LB;                   // counted vmem per stage
    __shared__ short Ald[2][BM * 64];
    __shared__ short Bld[2][BN * 64];

    const int tid = threadIdx.x, lane = tid & 63, w = tid >> 6;
    const int wr = w / NWC, wc = w % NWC;
    const int row0 = blockIdx.x * BM;
    const int l8 = lane >> 3;
    const int sx = (lane & 7) ^ l8;

    const short* Ahl = (const short*)Av;
    const float* Af  = (const float*)Av;
    const int arow = tid >> 2, aq = tid & 3;
    const int akey = arow & 7;

    f32x4 acc[4][NF] = {};

    auto stageB = [&](int t, int b) {
#pragma unroll
        for (int ch = w; ch < BN / 8; ch += 4)
            gload_lds16(Bhl + (size_t)(ch * 8 + l8) * (2 * K) + (size_t)t * 64 + sx * 8,
                        &Bld[b][ch * 512]);
    };
    auto stageAg = [&](int t, int b) {
#pragma unroll
        for (int ch = w; ch < BM / 8; ch += 4)
            gload_lds16(Ahl + (size_t)(row0 + ch * 8 + l8) * (2 * K) + (size_t)t * 64 + sx * 8,
                        &Ald[b][ch * 512]);
    };
    auto loadAf = [&](int t, float4& x0, float4& x1) {
        int gr = row0 + arow;
        x0 = make_float4(0.f, 0.f, 0.f, 0.f); x1 = x0;
        if (gr < N) {
            x0 = *(const float4*)&Af[(size_t)gr * K + t * 32 + aq * 8];
            x1 = *(const float4*)&Af[(size_t)gr * K + t * 32 + aq * 8 + 4];
        }
    };
    auto writeAf = [&](int b, float4 x0, float4 x1) {
        float f[8] = {x0.x, x0.y, x0.z, x0.w, x1.x, x1.y, x1.z, x1.w};
        short8_t hi, lo;
#pragma unroll
        for (int j = 0; j < 8; ++j) {
            short hh = bf16_hi(f[j]);
            hi[j] = hh;
            lo[j] = bf16_hi(f[j] - bf16_f32(hh));
        }
        *(short8_t*)&Ald[b][arow * 64 + ((2 * aq) ^ akey) * 8] = hi;
        *(short8_t*)&Ald[b][arow * 64 + ((2 * aq + 1) ^ akey) * 8] = lo;
    };

    // ---- prologue: two tiles in flight, wait only tile 0 ----
    float4 pxa[2], pxb[2];                 // AF32 A-register pipeline (3-deep)
    if constexpr (AF32) {
        float4 a0, a1, b0, b1;
        loadAf(0, a0, a1); stageB(0, 0); writeAf(0, a0, a1);
        loadAf(1, b0, b1); stageB(1, 1); writeAf(1, b0, b1);
        loadAf(2, pxa[0], pxb[0]);
        wait_vm(10);                       // leaves B(1)=8 + A(2)=2
        LGKM0();                           // ds_writes of tiles 0/1 retired
    } else {
        stageAg(0, 0); stageB(0, 0);
        stageAg(1, 1); stageB(1, 1);
        wait_vm(L);                        // tile 0 landed; tile 1 in flight
    }
    GBAR();

    // ---- main loop ----
#pragma unroll
    for (int t = 0; t < NT; ++t) {
        const int cur = t & 1;

        // compute(cur): frag reads + 3-term MFMA (compiler fine-grained lgkm)
        const int sH = (lane >> 4) * 2, sL2 = sH + 1;
        short8_t ah[4], al[4];
#pragma unroll
        for (int m = 0; m < 4; ++m) {
            int rl = wr * 64 + m * 16 + (lane & 15);
            int key = rl & 7;
            ah[m] = *(const short8_t*)&Ald[cur][rl * 64 + (sH ^ key) * 8];
            al[m] = *(const short8_t*)&Ald[cur][rl * 64 + (sL2 ^ key) * 8];
        }
#pragma unroll
        for (int n = 0; n < NF; ++n) {
            int cl = wc * (BN / NWC) + n * 16 + (lane & 15);
            int key = cl & 7;
            short8_t bh = *(const short8_t*)&Bld[cur][cl * 64 + (sH ^ key) * 8];
            short8_t bl = *(const short8_t*)&Bld[cur][cl * 64 + (sL2 ^ key) * 8];
#pragma unroll
            for (int m = 0; m < 4; ++m) {
                acc[m][n] = __builtin_amdgcn_mfma_f32_16x16x32_bf16(ah[m], bh, acc[m][n], 0, 0, 0);
                acc[m][n] = __builtin_amdgcn_mfma_f32_16x16x32_bf16(ah[m], bl, acc[m][n], 0, 0, 0);
                acc[m][n] = __builtin_amdgcn_mfma_f32_16x16x32_bf16(al[m], bh, acc[m][n], 0, 0, 0);
            }
        }

        GBAR();                            // all waves done reading cur
        if constexpr (AF32) {
            if (t + 3 < NT) loadAf(t + 3, pxa[(t + 1) & 1], pxb[(t + 1) & 1]);
            if (t + 2 < NT) {
                stageB(t + 2, cur);
                writeAf(cur, pxa[t & 1], pxb[t & 1]);   // A(t+2), loaded last iter
            }
            LGKM0();                       // ds_writes retired before barrier
            wait_vm((t + 3 < NT ? 2 : 0) + (t + 2 < NT ? LB : 0));
        } else {
            if (t + 2 < NT) { stageAg(t + 2, cur); stageB(t + 2, cur); }
            wait_vm(t + 2 < NT ? L : 0);   // t+1 landed; t+2 stays in flight
        }
        GBAR();
    }

    // ---- fused quant epilogue ----
    const int lg = lane >> 4, lc = lane & 15;
    float* maxb = (float*)&Ald[0][0];
    float rmax[4][4];
#pragma unroll
    for (int m = 0; m < 4; ++m)
#pragma unroll
        for (int r = 0; r < 4; ++r) {
            float v = 0.f;
#pragma unroll
            for (int n = 0; n < NF; ++n) v = fmaxf(v, fabsf(acc[m][n][r]));
#pragma unroll
            for (int o = 8; o >= 1; o >>= 1) v = fmaxf(v, __shfl_xor(v, o));
            rmax[m][r] = v;
        }
    if constexpr (NWC > 1) {
        __syncthreads();
        if (lc == 0)
#pragma unroll
            for (int m = 0; m < 4; ++m)
#pragma unroll
                for (int r = 0; r < 4; ++r)
                    maxb[(wr * 64 + m * 16 + lg * 4 + r) * NWC + wc] = rmax[m][r];
        __syncthreads();
    }
#pragma unroll
    for (int m = 0; m < 4; ++m)
#pragma unroll
        for (int r = 0; r < 4; ++r) {
            int rl = wr * 64 + m * 16 + lg * 4 + r;
            float v = rmax[m][r];
            if constexpr (NWC > 1) {
                v = maxb[rl * NWC];
#pragma unroll
                for (int q = 1; q < NWC; ++q) v = fmaxf(v, maxb[rl * NWC + q]);
            }
            int grow = row0 + rl;
            if (grow < N) {
                float inv = (v > 0.f) ? 32767.f / v : 0.f;
                if (lc == 0 && wc == 0) scl[grow] = v * (1.f / 32767.f);
#pragma unroll
                for (int n = 0; n < NF; ++n)
                    ZQ[(size_t)grow * BN + wc * (BN / NWC) + n * 16 + lc] =
                        (short)rintf(acc[m][n][r] * inv);
            }
        }
}

// ---------------- SpMM (CSR, padded rows), one wave per dest row -----------

// d=256, wide: lane loads short8 (16B); half h covers edge 2i+h.
__global__ __launch_bounds__(256) void spmm_agg256_k(const int* __restrict__ rowptr,
                                                     const int2* __restrict__ ecv,
                                                     const short* __restrict__ Q,
                                                     const float* __restrict__ scl,
                                                     short* __restrict__ Zhl, int N) {
    int row = blockIdx.x * 4 + (threadIdx.x >> 6);
    if (row >= N) return;
    const int lane = threadIdx.x & 63;
    const int half = lane >> 5;
    const int l32 = lane & 31;
    int s = rowptr[row], e = rowptr[row + 1];   // both %4
    const short8_t* Qv = (const short8_t*)Q;
    f32x4 a0 = {0.f, 0.f, 0.f, 0.f}, a1 = a0;
    for (int i = s; i < e; i += 4) {
        int4 A = *(const int4*)(ecv + i);
        int4 B = *(const int4*)(ecv + i + 2);
        int   cA = half ? A.z : A.x;
        float wA = __int_as_float(half ? A.w : A.y) * scl[cA];
        int   cB = half ? B.z : B.x;
        float wB = __int_as_float(half ? B.w : B.y) * scl[cB];
        short8_t qA = Qv[(size_t)cA * 32 + l32];
        short8_t qB = Qv[(size_t)cB * 32 + l32];
#pragma unroll
        for (int j = 0; j < 4; ++j) {
            a0[j] = fmaf(wA, (float)qA[j], a0[j]);
            a1[j] = fmaf(wA, (float)qA[j + 4], a1[j]);
            a0[j] = fmaf(wB, (float)qB[j], a0[j]);
            a1[j] = fmaf(wB, (float)qB[j + 4], a1[j]);
        }
    }
#pragma unroll
    for (int j = 0; j < 4; ++j) {
        a0[j] += __shfl_xor(a0[j], 32);
        a1[j] += __shfl_xor(a1[j], 32);
    }
    if (half == 0) {
        short8_t hi, lo;
#pragma unroll
        for (int j = 0; j < 4; ++j) {
            float r0 = fmaxf(a0[j], 0.f), r1 = fmaxf(a1[j], 0.f);
            short h0 = bf16_hi(r0), h1 = bf16_hi(r1);
            hi[j] = h0; hi[j + 4] = h1;
            lo[j] = bf16_hi(r0 - bf16_f32(h0));
            lo[j + 4] = bf16_hi(r1 - bf16_f32(h1));
        }
        size_t base = (size_t)row * 512 + l32 * 16;
        *(short8_t*)&Zhl[base] = hi;
        *(short8_t*)&Zhl[base + 8] = lo;
    }
}

// d=64, wide: lane loads short4 (8B); quarter q covers edge 4i+q.
__global__ __launch_bounds__(256) void spmm_softmax64_k(const int* __restrict__ rowptr,
                                                        const int2* __restrict__ ecv,
                                                        const short* __restrict__ Q,
                                                        const float* __restrict__ scl,
                                                        float* __restrict__ out, int N) {
    int row = blockIdx.x * 4 + (threadIdx.x >> 6);
    if (row >= N) return;
    const int lane = threadIdx.x & 63;
    const int q = lane >> 4;
    const int l16 = lane & 15;
    int s = rowptr[row], e = rowptr[row + 1];
    const short4_t* Qv = (const short4_t*)Q;
    f32x4 acc = {0.f, 0.f, 0.f, 0.f};
    for (int i = s; i < e; i += 4) {
        int4 A = *(const int4*)(ecv + i);
        int4 B = *(const int4*)(ecv + i + 2);
        int c = (q & 2) ? ((q & 1) ? B.z : B.x) : ((q & 1) ? A.z : A.x);
        int wbits = (q & 2) ? ((q & 1) ? B.w : B.y) : ((q & 1) ? A.w : A.y);
        float wv = __int_as_float(wbits) * scl[c];
        short4_t z = Qv[(size_t)c * 16 + l16];
#pragma unroll
        for (int j = 0; j < 4; ++j) acc[j] = fmaf(wv, (float)z[j], acc[j]);
    }
#pragma unroll
    for (int j = 0; j < 4; ++j) {
        acc[j] += __shfl_xor(acc[j], 16);
        acc[j] += __shfl_xor(acc[j], 32);
    }
    float m = fmaxf(fmaxf(acc[0], acc[1]), fmaxf(acc[2], acc[3]));
#pragma unroll
    for (int o = 8; o >= 1; o >>= 1) m = fmaxf(m, __shfl_xor(m, o));
    float p0 = __expf(acc[0] - m), p1 = __expf(acc[1] - m);
    float p2 = __expf(acc[2] - m), p3 = __expf(acc[3] - m);
    float ssum = p0 + p1 + p2 + p3;
#pragma unroll
    for (int o = 8; o >= 1; o >>= 1) ssum += __shfl_xor(ssum, o);
    if (q == 0) {
        float inv = 1.f / ssum;
        float4 o4 = make_float4(p0 * inv, p1 * inv, p2 * inv, p3 * inv);
        *(float4*)&out[(size_t)row * 64 + l16 * 4] = o4;
    }
}

// ---------------------------------------------------------------------------

extern "C" void kernel_launch(void* const* d_in, const int* in_sizes, int n_in,
                              void* d_out, int out_size, void* d_ws, size_t ws_size,
                              hipStream_t stream) {
    const float* X        = (const float*)d_in[0];
    const int*   edge_row = (const int*)d_in[1];
    const int*   edge_col = (const int*)d_in[2];
    const float* edge_val = (const float*)d_in[3];
    const float* W0       = (const float*)d_in[4];
    const float* Wh1      = (const float*)d_in[5];
    const float* W1       = (const float*)d_in[6];

    const int C = 512, H = 256, F = 64;
    const int N = in_sizes[0] / C;     // 100000
    const int E = in_sizes[1];         // 3200000
    const int EPAD = E + 4 * N + 64;   // padded-edge capacity

    size_t off = 0;
    auto alloc = [&](size_t bytes) -> void* {
        void* p = (char*)d_ws + off;
        off += (bytes + 255) & ~(size_t)255;
        return p;
    };
    short* Zhl    = (short*)alloc((size_t)N * 2 * H * sizeof(short));  // 102.4MB
    short* ZQ     = (short*)alloc((size_t)N * H * sizeof(short));      // 51.2MB
    float* scl    = (float*)alloc((size_t)N * sizeof(float));
    int*   deg    = (int*)alloc((size_t)N * sizeof(int));
    int*   rowptr = (int*)alloc((size_t)(N + 1) * sizeof(int));
    int*   cursor = (int*)alloc((size_t)N * sizeof(int));
    int*   bsum   = (int*)alloc(129 * sizeof(int));
    int2*  ecv    = (int2*)alloc((size_t)EPAD * sizeof(int2));
    short* Bhl0   = (short*)alloc((size_t)H * 2 * C * sizeof(short));  // [256][1024]
    short* Bhl1   = (short*)alloc((size_t)H * 2 * H * sizeof(short));  // [256][512]
    short* Bhl2   = (short*)alloc((size_t)F * 2 * H * sizeof(short));  // [64][512]
    (void)ws_size;

    // ---- build padded CSR ----
    hipMemsetAsync(deg, 0, (size_t)N * sizeof(int), stream);
    hipMemsetAsync(ecv, 0, (size_t)EPAD * sizeof(int2), stream);
    count_rows_k<<<(E + 255) / 256, 256, 0, stream>>>(edge_row, deg, E);
    int nb = (N + SCAN_B - 1) / SCAN_B;          // 98 <= 128
    scan1_k<<<nb, SCAN_B, 0, stream>>>(deg, rowptr, bsum, N);
    scan2_k<<<1, 128, 0, stream>>>(bsum, nb);
    scan3_k<<<nb, SCAN_B, 0, stream>>>(rowptr, bsum, cursor, N, nb);
    const int gsz = (N + 7) / 8;                 // 12500 rows per XCD group
    scatter_xcd_k<<<8 * 256, 256, 0, stream>>>(edge_row, edge_col, edge_val,
                                               cursor, ecv, E, gsz);

    // ---- prep weights ----
    split_w_k<<<(C * H + 255) / 256, 256, 0, stream>>>(W0, Bhl0, C, H);
    split_w_k<<<(H * H + 255) / 256, 256, 0, stream>>>(Wh1, Bhl1, H, H);
    split_w_k<<<(H * F + 255) / 256, 256, 0, stream>>>(W1, Bhl2, H, F);

    const int g64  = (N + 63) / 64;              // 1563
    const int g128 = (N + 127) / 128;            // 782
    const int rg   = (N + 3) / 4;                // 25000

    // ---- layer 0 ----
    gemm_hl<512, 256, 1, 4, true><<<g64, 256, 0, stream>>>(X, Bhl0, ZQ, scl, N);
    spmm_agg256_k<<<rg, 256, 0, stream>>>(rowptr, ecv, ZQ, scl, Zhl, N);
    // ---- layer 1 ----
    gemm_hl<256, 256, 1, 4, false><<<g64, 256, 0, stream>>>(Zhl, Bhl1, ZQ, scl, N);
    spmm_agg256_k<<<rg, 256, 0, stream>>>(rowptr, ecv, ZQ, scl, Zhl, N);
    // ---- layer 2 ----
    gemm_hl<256, 64, 2, 2, false><<<g128, 256, 0, stream>>>(Zhl, Bhl2, ZQ, scl, N);
    spmm_softmax64_k<<<rg, 256, 0, stream>>>(rowptr, ecv, ZQ, scl,
                                             (float*)d_out, N);
}